// Round 5
// baseline (221.259 us; speedup 1.0000x reference)
//
#include <hip/hip_runtime.h>
#include <math.h>

#define BB 4
#define HH 8
#define NN 2048
#define DD 64
#define KTOP 16
#define CUT_MARGIN 1e-3f

typedef _Float16 half_t;
typedef __attribute__((ext_vector_type(8))) _Float16 half8;
typedef __attribute__((ext_vector_type(4))) float floatx4;

// async 16B global->LDS copy (hardware scatters lane i at ldsbase + i*16)
__device__ __forceinline__ void gl_lds16(const half_t* g, half_t* l) {
    __builtin_amdgcn_global_load_lds(
        (const __attribute__((address_space(1))) void*)g,
        (__attribute__((address_space(3))) void*)l, 16, 0, 0);
}

// ---------------------------------------------------------------------------
// Kernel 0: split fp32 q,k into f16 hi + f16 (lo*2^11).
// Layout: per (b,h,kb) plane (kb = d/32), 16 tiles of 128 rows; each 8KB
// tile stored PRE-SWIZZLED in phys-unit order p(r,kg) = (r>>3)*32 + kg*8
// + (r&7)  (16B units; kg = (d>>3)&3). Gemm then stages identity-linear
// (fully coalesced) and reads conflict-free (v4-verified: 0 conflicts).
// ---------------------------------------------------------------------------
__global__ __launch_bounds__(256) void split_swz(const float* __restrict__ q,
                                                 const float* __restrict__ kk,
                                                 half_t* __restrict__ qhi,
                                                 half_t* __restrict__ qlo,
                                                 half_t* __restrict__ khi,
                                                 half_t* __restrict__ klo) {
    const int uidx = blockIdx.x * 256 + threadIdx.x;  // 16B-unit index
    const size_t src = (size_t)uidx * 8;
    const int R   = uidx >> 3;          // global row over B*H*N
    const int kg8 = uidx & 7;           // which 8-float group (d = kg8*8..+7)
    const int bh  = R >> 11;            // b*H + h   (N = 2048)
    const int n   = R & 2047;
    const int kb  = kg8 >> 2;           // k-block (d>>5)
    const int kgw = kg8 & 3;            // 8-group within k-block
    const int tile = n >> 7;
    const int r    = n & 127;
    const int p    = ((r >> 3) << 5) + (kgw << 3) + (r & 7);
    const size_t dst = (((size_t)(bh * 2 + kb) * 16 + tile) * 512 + p) * 8;

    float a[8], b[8];
    *(float4*)&a[0] = *(const float4*)(q + src);
    *(float4*)&a[4] = *(const float4*)(q + src + 4);
    *(float4*)&b[0] = *(const float4*)(kk + src);
    *(float4*)&b[4] = *(const float4*)(kk + src + 4);
    half8 qh, ql, kh, kl;
#pragma unroll
    for (int e = 0; e < 8; ++e) {
        half_t hq = (half_t)a[e];
        half_t hk = (half_t)b[e];
        qh[e] = hq; ql[e] = (half_t)((a[e] - (float)hq) * 2048.0f);
        kh[e] = hk; kl[e] = (half_t)((b[e] - (float)hk) * 2048.0f);
    }
    *(half8*)(qhi + dst) = qh;
    *(half8*)(qlo + dst) = ql;
    *(half8*)(khi + dst) = kh;
    *(half8*)(klo + dst) = kl;
}

// ---------------------------------------------------------------------------
// Kernel 1 (v5): m201-style 8-wave multi-phase schedule.
// Tile 256x128, 512 threads (8 waves as 4Mx2N), per-wave 64x64 output.
// Triple-buffered LDS (3 x 48KB = 144KB, 1 block/CU): step s reads buf s%3,
// tile s+1 already landed, tile s+2 streams into buf (s+2)%3 -- staging
// never touches a live buffer. Per K-step, 4 phases (one 16-row strip
// each): {ds_read frags | issue 1-2 global_load_lds -> barrier ->
// lgkmcnt(0) -> setprio -> 12 MFMAs -> setprio -> barrier}. vmcnt(6)
// once per step (phase 3), never drained in the main loop (T3+T4).
// LDS per-buffer map (halfs): [0,8192) Ah, [8192,16384) Al,
// [16384,20480) Bh, [20480,24576) Bl. Staging chunk c (=wave*6+q) lands
// at c*512 exactly. Accumulation order bit-identical to v4 (absmax 0.0).
// ---------------------------------------------------------------------------
__global__ __launch_bounds__(512, 2) void gemm_f16x3(const half_t* __restrict__ qhi,
                                                     const half_t* __restrict__ qlo,
                                                     const half_t* __restrict__ khi,
                                                     const half_t* __restrict__ klo,
                                                     float* __restrict__ L) {
    const int b  = blockIdx.z;
    const int i0 = blockIdx.y * 256;
    const int j0 = blockIdx.x * 128;
    const int tid  = threadIdx.x;
    const int wave = __builtin_amdgcn_readfirstlane(tid >> 6);
    const int lane = tid & 63;
    const int wr = wave >> 1, wc = wave & 1;   // 4 x 2 wave grid
    const int lm = lane & 15, quad = lane >> 4;

    __shared__ __align__(16) half_t lds[3 * 24576];   // 144 KB

    // conflict-free frag read offsets (v4-verified pattern)
    int aidx[4], bidx[4];
#pragma unroll
    for (int t = 0; t < 4; ++t) {
        const int am = wr * 64 + t * 16 + lm;          // [0,256)
        const int bm = wc * 64 + t * 16 + lm;          // [0,128)
        aidx[t] = ((am >> 3) << 8) + (quad << 6) + ((am & 7) << 3);
        bidx[t] = 16384 + ((bm >> 3) << 8) + (quad << 6) + ((bm & 7) << 3);
    }

    // staging setup: wave w owns chunks c = w*6 .. w*6+5 of the 48KB tile
    const size_t tileA = (size_t)(i0 >> 7) * 4096;     // 2 consecutive 8KB tiles
    const size_t tileB = (size_t)(j0 >> 7) * 4096;     // 1 8KB tile
    const size_t bbase = (size_t)(b * 16) * 65536;     // plane stride 65536 halfs
    const half_t* gq[6];
    int lq[6];
#pragma unroll
    for (int q = 0; q < 6; ++q) {
        const int c = wave * 6 + q;
        const half_t* base;
        size_t off;
        if (c < 16)      { base = qhi; off = tileA + (size_t)c * 512; }
        else if (c < 32) { base = qlo; off = tileA + (size_t)(c - 16) * 512; }
        else if (c < 40) { base = khi; off = tileB + (size_t)(c - 32) * 512; }
        else             { base = klo; off = tileB + (size_t)(c - 40) * 512; }
        gq[q] = base + bbase + off + lane * 8;
        lq[q] = c * 512;
    }

#define ISSUE(q_, s_, nb_)                                                    \
    gl_lds16(gq[q_] + (size_t)(s_) * 65536, &lds[(nb_) * 24576 + lq[q_]])

#define WAITL0 { asm volatile("s_waitcnt lgkmcnt(0)" ::: "memory");           \
                 __builtin_amdgcn_sched_barrier(0); }
#define WAITV6 { asm volatile("s_waitcnt vmcnt(6)" ::: "memory");             \
                 __builtin_amdgcn_sched_barrier(0); }
#define WAITV0 { asm volatile("s_waitcnt vmcnt(0)" ::: "memory");             \
                 __builtin_amdgcn_sched_barrier(0); }
#define BAR    { __builtin_amdgcn_s_barrier();                                \
                 __builtin_amdgcn_sched_barrier(0); }

#define MF(tr_)                                                               \
    {                                                                         \
        __builtin_amdgcn_s_setprio(1);                                        \
        _Pragma("unroll") for (int tc = 0; tc < 4; ++tc) {                    \
            acc1[tr_][tc] = __builtin_amdgcn_mfma_f32_16x16x32_f16(           \
                ah, bh[tc], acc1[tr_][tc], 0, 0, 0);                          \
            acc2[tr_][tc] = __builtin_amdgcn_mfma_f32_16x16x32_f16(           \
                ah, bl[tc], acc2[tr_][tc], 0, 0, 0);                          \
            acc2[tr_][tc] = __builtin_amdgcn_mfma_f32_16x16x32_f16(           \
                al, bh[tc], acc2[tr_][tc], 0, 0, 0);                          \
        }                                                                     \
        __builtin_amdgcn_s_setprio(0);                                        \
    }

    floatx4 acc1[4][4], acc2[4][4];
#pragma unroll
    for (int tr = 0; tr < 4; ++tr)
#pragma unroll
        for (int tc = 0; tc < 4; ++tc) {
            acc1[tr][tc] = (floatx4)0.0f;
            acc2[tr][tc] = (floatx4)0.0f;
        }

    // ---- prologue: stage tiles 0,1 (12 calls/wave); wait tile 0 only ----
#pragma unroll
    for (int q = 0; q < 6; ++q) ISSUE(q, 0, 0);
#pragma unroll
    for (int q = 0; q < 6; ++q) ISSUE(q, 1, 1);
    WAITV6;
    BAR;

    // ---- 16 K-steps, 4 phases each; vmcnt(6) once per step ----
#pragma unroll
    for (int s = 0; s < 16; ++s) {
        const int bb = (s % 3) * 24576;
        const int nb = (s + 2) % 3;
        half8 bh[4], bl[4], ah, al;
        // ---- phase 0: B frags + A strip 0; issue 2 stage calls ----
#pragma unroll
        for (int t = 0; t < 4; ++t) {
            bh[t] = *(const half8*)&lds[bb + bidx[t]];
            bl[t] = *(const half8*)&lds[bb + 4096 + bidx[t]];
        }
        ah = *(const half8*)&lds[bb + aidx[0]];
        al = *(const half8*)&lds[bb + 8192 + aidx[0]];
        if (s < 14) { ISSUE(0, s + 2, nb); ISSUE(1, s + 2, nb); }
        BAR; WAITL0;
        MF(0);
        BAR;
        // ---- phase 1 ----
        ah = *(const half8*)&lds[bb + aidx[1]];
        al = *(const half8*)&lds[bb + 8192 + aidx[1]];
        if (s < 14) { ISSUE(2, s + 2, nb); ISSUE(3, s + 2, nb); }
        BAR; WAITL0;
        MF(1);
        BAR;
        // ---- phase 2 ----
        ah = *(const half8*)&lds[bb + aidx[2]];
        al = *(const half8*)&lds[bb + 8192 + aidx[2]];
        if (s < 14) { ISSUE(4, s + 2, nb); }
        BAR; WAITL0;
        MF(2);
        BAR;
        // ---- phase 3: last stage call + the step's single vmcnt ----
        ah = *(const half8*)&lds[bb + aidx[3]];
        al = *(const half8*)&lds[bb + 8192 + aidx[3]];
        if (s < 14) { ISSUE(5, s + 2, nb); }
        if (s < 14) { WAITV6; }                 // tile s+1 landed; s+2 in flight
        else if (s == 14) { WAITV0; }           // drain final tile 15
        BAR; WAITL0;
        MF(3);
        if (s < 15) BAR;
    }

#undef ISSUE
#undef WAITL0
#undef WAITV6
#undef WAITV0
#undef BAR
#undef MF

    const float s1 = 0.015625f;
    const float s2 = 0.015625f / 2048.0f;
#pragma unroll
    for (int tr = 0; tr < 4; ++tr)
#pragma unroll
        for (int r = 0; r < 4; ++r) {
            const int grow = i0 + wr * 64 + tr * 16 + quad * 4 + r;
            float* Lp = L + ((size_t)b * NN + grow) * NN + j0 + wc * 64 + lm;
#pragma unroll
            for (int tc = 0; tc < 4; ++tc)
                Lp[tc * 16] = acc1[tr][tc][r] * s1 + acc2[tr][tc][r] * s2;
        }
}

// ---------------------------------------------------------------------------
// Kernel 2: 4 independent rows per 256-thread block (one wave each) --
// wave-local algorithm, passed with absmax 0.0. Unchanged.
// ---------------------------------------------------------------------------
__device__ __forceinline__ unsigned long long flip64(double x) {
    unsigned long long v = (unsigned long long)__double_as_longlong(x);
    return v ^ ((0ULL - (v >> 63)) | 0x8000000000000000ULL);
}
__device__ __forceinline__ double unflip64(unsigned long long k) {
    unsigned long long v = (k >> 63) ? (k ^ 0x8000000000000000ULL) : ~k;
    return __longlong_as_double((long long)v);
}

__global__ __launch_bounds__(256) void topk_mask(float* __restrict__ LM,
                                                 const float* __restrict__ u) {
    const int wave = threadIdx.x >> 6;     // 0..3 (independent rows)
    const int lane = threadIdx.x & 63;     // 0..63, one wave
    const int row  = blockIdx.x * 4 + wave;
    float* lrow = LM + (size_t)row * NN;
    const float* urow = u + (size_t)row * NN;

    __shared__ int s_idx[4][64];

    // ---- phase A: stream row, keep only z + hard bitmask ----
    float z[32];
    unsigned hard = 0;
    float4 lb = *(const float4*)(lrow + lane * 4);
    float4 ub = *(const float4*)(urow + lane * 4);
#pragma unroll
    for (int e = 0; e < 8; ++e) {
        float4 lnx, unx;
        if (e < 7) {
            lnx = *(const float4*)(lrow + (e + 1) * 256 + lane * 4);
            unx = *(const float4*)(urow + (e + 1) * 256 + lane * 4);
        }
        const float* ls = (const float*)&lb;
        const float* us = (const float*)&ub;
#pragma unroll
        for (int s = 0; s < 4; ++s) {
            float w = -__logf(us[s] + 1e-9f);
            z[e * 4 + s] = ls[s] - __logf(w + 1e-9f);
            hard |= (us[s] > 0.999f ? 1u : 0u) << (e * 4 + s);
        }
        lb = lnx; ub = unx;
    }

    // ---- phase B: cutoff = (16th largest of 64 lane-maxima) - margin ----
    float v = z[0];
#pragma unroll
    for (int r = 1; r < 32; ++r) v = fmaxf(v, z[r]);
#pragma unroll
    for (int kS = 2; kS <= 64; kS <<= 1) {
#pragma unroll
        for (int j = kS >> 1; j > 0; j >>= 1) {
            float o = __shfl_xor(v, j, 64);
            bool asc = ((lane & kS) == 0);
            bool lower = ((lane & j) == 0);
            float mn = fminf(v, o), mx = fmaxf(v, o);
            v = (asc == lower) ? mn : mx;
        }
    }
    const float cut = __shfl(v, 48, 64) - CUT_MARGIN;

    // ---- phase C: ballot-prefix candidate gather (indices only) ----
    int c = 0;
#pragma unroll
    for (int r = 0; r < 32; ++r) {
        bool p = (z[r] >= cut);
        unsigned long long m = __ballot(p);
        if (p) {
            int slot = c + __popcll(m & ((1ULL << lane) - 1ULL));
            if (slot < 64) s_idx[wave][slot] = (r >> 2) * 256 + lane * 4 + (r & 3);
        }
        c += __popcll(m);
    }
    if (c > 64) c = 64;

    // ---- phase D: f64 keys; fixed 64-wide bitonic sort (ascending);
    //      threshold = sorted lane c-16 (exact 16th-largest z64) ----
    unsigned long long key = 0xFFFFFFFFFFFFFFFFULL;
    if (lane < c) {
        int idx = s_idx[wave][lane];
        double uu = (double)urow[idx] + 1e-9;   // cache-hot gather
        double w  = -log(uu);
        double g  = -log(w + 1e-9);
        key = flip64((double)lrow[idx] + g);
    }
#pragma unroll
    for (int kS = 2; kS <= 64; kS <<= 1) {
#pragma unroll
        for (int j = kS >> 1; j > 0; j >>= 1) {
            unsigned long long o = __shfl_xor(key, j, 64);
            bool asc = ((lane & kS) == 0);
            bool lower = ((lane & j) == 0);
            unsigned long long mn = (key < o) ? key : o;
            unsigned long long mx = (key < o) ? o : key;
            key = (asc == lower) ? mn : mx;
        }
    }
    const double thresh = unflip64(__shfl(key, c - KTOP, 64));

    // ---- phase E0: band|hard elements resolved in f64 ONCE, patch z ----
    const float t_hi = (float)thresh + 3e-4f;
    const float t_lo = (float)thresh - 3e-4f;
    unsigned bm = hard;
#pragma unroll
    for (int r = 0; r < 32; ++r)
        bm |= ((z[r] <= t_hi && z[r] >= t_lo) ? 1u : 0u) << r;
    while (bm) {           // expected ~0-2 iterations per wave, sparse exec
        int t = __builtin_ctz(bm);
        bm &= bm - 1;
        const int idx = (t >> 2) * 256 + lane * 4 + (t & 3);
        double uu = (double)urow[idx] + 1e-9;
        double w  = -log(uu);
        double g  = -log(w + 1e-9);
        double z64 = (double)lrow[idx] + g;    // L still intact (no stores yet)
        z[t] = (z64 >= thresh) ? 1.0e30f : -1.0e30f;
    }

    // ---- phase E1: pure-f32 store pass ----
#pragma unroll
    for (int e = 0; e < 8; ++e) {
        float o[4];
#pragma unroll
        for (int s = 0; s < 4; ++s)
            o[s] = (z[e * 4 + s] > t_hi) ? 1.0f : 0.0f;
        *(float4*)(lrow + e * 256 + lane * 4) = *(float4*)o;
    }
}

extern "C" void kernel_launch(void* const* d_in, const int* in_sizes, int n_in,
                              void* d_out, int out_size, void* d_ws, size_t ws_size,
                              hipStream_t stream) {
    const float* q = (const float*)d_in[0];
    const float* k = (const float*)d_in[1];
    const float* u = (const float*)d_in[2];
    float* out = (float*)d_out;          // logits scratch, then final mask
    const size_t NQ = (size_t)BB * HH * NN * DD;   // 4M elements
    half_t* qhi = (half_t*)d_ws;
    half_t* qlo = qhi + NQ;
    half_t* khi = qlo + NQ;
    half_t* klo = khi + NQ;              // 32 MB total in d_ws

    split_swz<<<(int)(NQ / 8 / 256), 256, 0, stream>>>(q, k, qhi, qlo, khi, klo);

    dim3 grid1(NN / 128, NN / 256, BB);
    gemm_f16x3<<<grid1, 512, 0, stream>>>(qhi, qlo, khi, klo, out);

    topk_mask<<<BB * NN / 4, 256, 0, stream>>>(out, u);
}